// Round 16
// baseline (1341.058 us; speedup 1.0000x reference)
//
#include <hip/hip_runtime.h>

typedef unsigned short u16;
typedef unsigned int u32;
typedef __attribute__((ext_vector_type(8))) short bf16x8;
typedef __attribute__((ext_vector_type(4))) float f32x4;

// B=64 T=20 D_IN=512 H=512 D_ENC=2048 P=196 D_ATT=512
#define NB 64
#define NT 20
#define NH 512
#define NP 196
#define NE 2048
#define NA 512

__device__ __forceinline__ u16 f2bf(float f) {
  u32 b = __float_as_uint(f);
  return (u16)((b + 0x7FFFu + ((b >> 16) & 1u)) >> 16);
}
__device__ __forceinline__ float bf2f(u16 u) { return __uint_as_float(((u32)u) << 16); }
__device__ __forceinline__ float tanh_fast(float x) {
  float xc = fminf(fmaxf(x, -15.f), 15.f);
  float e2 = __builtin_amdgcn_exp2f(xc * 2.885390082f);
  return (e2 - 1.f) * __builtin_amdgcn_rcpf(e2 + 1.f);
}
__device__ __forceinline__ float sigmoid_fast(float x) {
  return __builtin_amdgcn_rcpf(1.f + __builtin_amdgcn_exp2f(x * -1.44269504f));
}

__device__ __forceinline__ void gload_lds16(const u16* g, u16* l) {
  __builtin_amdgcn_global_load_lds((const __attribute__((address_space(1))) void*)g,
                                   (__attribute__((address_space(3))) void*)l, 16, 0, 0);
}

template <int N>
__device__ __forceinline__ void vwait() {
  if constexpr (N >= 0)
    asm volatile("s_waitcnt vmcnt(%0)" ::"i"(N) : "memory");
  else
    asm volatile("" ::: "memory");
}

// ===== prep_all: cnn->bf16 (J0), x->xbT (J1), all weight transposes (J2..) in ONE launch =====
// J0 [0,2048):        conv cnn (grid-stride over 6422528 float4)
// J1 [2048,2688):     conv_x   (163840 float4, 1 per thread)
// J2 [2688,2688+7424): transposes (job table identical to R15 transpose_all)
__global__ __launch_bounds__(256) void prep_all(
    const float4* __restrict__ cnn4, const float* __restrict__ x, const float* __restrict__ Wi,
    const float* __restrict__ Wf, const float* __restrict__ Wc, const float* __restrict__ Wo,
    const float* __restrict__ Waf, const float* __restrict__ Wah, u16* __restrict__ cnnb,
    u16* __restrict__ xbT, u16* __restrict__ wxt, u16* __restrict__ wbig,
    u16* __restrict__ wcombT) {
  const int blk = blockIdx.x, tid = threadIdx.x;
  __shared__ float tile[32][33];
  if (blk < 2048) {
    const int n4 = (NB * NP * NE) / 4;
    for (int i = blk * 256 + tid; i < n4; i += 2048 * 256) {
      float4 v = cnn4[i];
      u32 lo = (u32)f2bf(v.x) | ((u32)f2bf(v.y) << 16);
      u32 hi = (u32)f2bf(v.z) | ((u32)f2bf(v.w) << 16);
      *(uint2*)(cnnb + (size_t)i * 4) = make_uint2(lo, hi);
    }
    return;
  }
  if (blk < 2688) {
    const int j = (blk - 2048) * 256 + tid;  // < 163840
    float4 v = ((const float4*)x)[j];
    const int bt = j >> 7, c = j & 127;
    const int b = bt / 20, t = bt - b * 20;
    u32 lo = (u32)f2bf(v.x) | ((u32)f2bf(v.y) << 16);
    u32 hi = (u32)f2bf(v.z) | ((u32)f2bf(v.w) << 16);
    *(uint2*)(xbT + ((size_t)t * NB + b) * 512 + c * 4) = make_uint2(lo, hi);
    return;
  }
  const int tb = blk - 2688;
  const float* src;
  u16* dst;
  int row_off, K, bx, by;
  if (tb < 1024) {
    int z = tb >> 8, r = tb & 255;
    bx = r & 15;
    by = r >> 4;
    src = z == 0 ? Wi : z == 1 ? Wf : z == 2 ? Wc : Wo;
    dst = wxt + (size_t)z * 512 * 512;
    row_off = 0;
    K = 512;
  } else if (tb < 2048) {
    int r = tb - 1024;
    bx = r & 63;
    by = r >> 6;
    src = Waf;
    dst = wbig;
    row_off = 0;
    K = 2048;
  } else if (tb < 6144) {
    int r = tb - 2048;
    int z = r >> 10, r2 = r & 1023;
    bx = r2 & 63;
    by = r2 >> 6;
    src = z == 0 ? Wi : z == 1 ? Wf : z == 2 ? Wc : Wo;
    dst = wbig + (size_t)512 * 2048 + (size_t)z * 512 * 2048;
    row_off = 1024;
    K = 2048;
  } else if (tb < 7168) {
    int r = tb - 6144;
    int z = r >> 8, r2 = r & 255;
    bx = r2 & 15;
    by = r2 >> 4;
    src = z == 0 ? Wi : z == 1 ? Wf : z == 2 ? Wc : Wo;
    dst = wcombT + (size_t)z * 512 * 512;
    row_off = 512;
    K = 512;
  } else {
    int r = tb - 7168;
    bx = r & 15;
    by = r >> 4;
    src = Wah;
    dst = wcombT + (size_t)2048 * 512;
    row_off = 0;
    K = 512;
  }
  const int k0 = bx * 32, n0 = by * 32;
  const int tx = tid & 31, ty = tid >> 5;  // 32 x 8
#pragma unroll
  for (int i = 0; i < 4; ++i)
    tile[ty + i * 8][tx] = src[(size_t)(row_off + k0 + ty + i * 8) * 512 + n0 + tx];
  __syncthreads();
#pragma unroll
  for (int i = 0; i < 4; ++i) {
    int n = n0 + ty + i * 8, k = k0 + tx;
    dst[(size_t)n * K + k] = f2bf(tile[tx][ty + i * 8]);
  }
}

// ------------- 128^2 bf16 MFMA GEMM (global_load_lds staging), f32 out: xw -------------
__global__ __launch_bounds__(256) void gemm_bf16(const u16* __restrict__ A,
                                                 const u16* __restrict__ BT,
                                                 float* __restrict__ C, int M, int N, int K) {
  __shared__ u16 lA[128 * 64];
  __shared__ u16 lB[128 * 64];
  const int tid = threadIdx.x;
  const int lane = tid & 63;
  const int wid = tid >> 6;
  const int m0 = blockIdx.x * 128, n0 = blockIdx.y * 128;
  const int wm = (wid >> 1) * 64, wn = (wid & 1) * 64;
  f32x4 acc[4][4] = {};

  const int cbase = wid * 256;  // wave-uniform
  int srcr[4], srcc[4];
#pragma unroll
  for (int it = 0; it < 4; ++it) {
    int c = cbase + it * 64 + lane;
    srcr[it] = c >> 3;
    srcc[it] = ((c & 7) ^ ((c >> 3) & 7)) * 8;
  }

  for (int k0 = 0; k0 < K; k0 += 64) {
    __syncthreads();
#pragma unroll
    for (int it = 0; it < 4; ++it) {
      gload_lds16(A + (size_t)(m0 + srcr[it]) * K + k0 + srcc[it],
                  lA + (size_t)(cbase + it * 64) * 8);
      gload_lds16(BT + (size_t)(n0 + srcr[it]) * K + k0 + srcc[it],
                  lB + (size_t)(cbase + it * 64) * 8);
    }
    __syncthreads();
#pragma unroll
    for (int kk = 0; kk < 2; ++kk) {
      int kchunk = kk * 4 + (lane >> 4);
      bf16x8 af[4], bg[4];
#pragma unroll
      for (int i = 0; i < 4; ++i) {
        int row = wm + i * 16 + (lane & 15);
        af[i] = *(const bf16x8*)(lA + row * 64 + ((kchunk ^ (row & 7)) * 8));
        int rowb = wn + i * 16 + (lane & 15);
        bg[i] = *(const bf16x8*)(lB + rowb * 64 + ((kchunk ^ (rowb & 7)) * 8));
      }
#pragma unroll
      for (int i = 0; i < 4; ++i)
#pragma unroll
        for (int j = 0; j < 4; ++j)
          acc[i][j] = __builtin_amdgcn_mfma_f32_16x16x32_bf16(af[i], bg[j], acc[i][j], 0, 0, 0);
    }
  }
#pragma unroll
  for (int i = 0; i < 4; ++i) {
    int m = m0 + wm + i * 16 + ((lane >> 4) * 4);
#pragma unroll
    for (int j = 0; j < 4; ++j) {
      int n = n0 + wn + j * 16 + (lane & 15);
#pragma unroll
      for (int r = 0; r < 4; ++r) C[(size_t)(m + r) * N + n] = acc[i][j][r];
    }
  }
}

// ------- 256^2 bf16 MFMA GEMM (R11/R15 version): wave owns 128x64, double-buffered LDS -------
#define STG(SS, CUR, K1)                                                                    \
  do {                                                                                      \
    _Pragma("unroll") for (int q_ = 0; q_ < 2; ++q_) {                                      \
      const u16* g_ = ((SS) < 2)                                                            \
                          ? (A + (size_t)(m0 + sR[SS][q_]) * K + (K1) + sC[SS][q_])         \
                          : (BT + (size_t)(n0 + sR[SS][q_]) * K + (K1) + sC[SS][q_]);       \
      gload_lds16(g_, lds + ((CUR) ^ 1) * 32768 + sL[SS][q_]);                              \
    }                                                                                       \
  } while (0)

#define PH(MF0, READB, CUR, DOSTAGE, SB, K1, WN)                                            \
  do {                                                                                      \
    const u16* pA_ = lds + (CUR) * 32768;                                                   \
    const u16* pB_ = pA_ + 16384;                                                           \
    bf16x8 af_[2][2];                                                                       \
    _Pragma("unroll") for (int kh_ = 0; kh_ < 2; ++kh_) {                                   \
      const int kc_ = kh_ * 4 + (lane >> 4);                                                \
      _Pragma("unroll") for (int ii_ = 0; ii_ < 2; ++ii_) {                                 \
        const int rA_ = wmH * 128 + ((MF0) + ii_) * 16 + l15;                               \
        af_[kh_][ii_] = *(const bf16x8*)(pA_ + rA_ * 64 + ((kc_ ^ (rA_ & 7)) * 8));         \
      }                                                                                     \
      if (READB) {                                                                          \
        _Pragma("unroll") for (int j_ = 0; j_ < 4; ++j_) {                                  \
          const int rB_ = wnq * 64 + j_ * 16 + l15;                                         \
          bg[kh_][j_] = *(const bf16x8*)(pB_ + rB_ * 64 + ((kc_ ^ (rB_ & 7)) * 8));         \
        }                                                                                   \
      }                                                                                     \
    }                                                                                       \
    if (DOSTAGE) {                                                                          \
      STG(SB, CUR, K1);                                                                     \
      STG((SB) + 1, CUR, K1);                                                               \
    }                                                                                       \
    vwait<WN>();                                                                            \
    __builtin_amdgcn_s_barrier();                                                           \
    __builtin_amdgcn_s_setprio(1);                                                          \
    _Pragma("unroll") for (int kh_ = 0; kh_ < 2; ++kh_)                                     \
      _Pragma("unroll") for (int ii_ = 0; ii_ < 2; ++ii_)                                   \
        _Pragma("unroll") for (int j_ = 0; j_ < 4; ++j_)                                    \
          acc[(MF0) + ii_][j_] = __builtin_amdgcn_mfma_f32_16x16x32_bf16(                   \
              af_[kh_][ii_], bg[kh_][j_], acc[(MF0) + ii_][j_], 0, 0, 0);                   \
    __builtin_amdgcn_s_setprio(0);                                                          \
    __builtin_amdgcn_s_barrier();                                                           \
  } while (0)

__global__ __launch_bounds__(512, 2) void gemm256(const u16* __restrict__ A,
                                                  const u16* __restrict__ BT,
                                                  const float* __restrict__ bias,
                                                  u16* __restrict__ fpb, u16* __restrict__ cnW,
                                                  int K, int grid_n) {
  __shared__ u16 lds[65536];  // [buf][A 256x64 | B 256x64] u16 = 128 KiB
  const int tid = threadIdx.x;
  const int lane = tid & 63;
  const int wid = tid >> 6;
  const int l15 = lane & 15;
  // bijective XCD-chunked swizzle (m204)
  const int nblk = gridDim.x;
  const int q = nblk >> 3, rr = nblk & 7;
  const int xcd = blockIdx.x & 7, jj = blockIdx.x >> 3;
  const int swz = (xcd < rr ? xcd * (q + 1) : rr * (q + 1) + (xcd - rr) * q) + jj;
  const int mt = swz / grid_n, nt = swz - mt * grid_n;
  const int m0 = mt * 256, n0 = nt * 256;
  const int wmH = wid >> 2;  // A-half (0/1): rows wmH*128..+128
  const int wnq = wid & 3;   // B quarter: cols wnq*64..+64
  f32x4 acc[8][4] = {};
  bf16x8 bg[2][4];  // B-frags read once per K-tile (ph0), carried through ph1-3

  int sR[4][2], sC[4][2], sL[4][2];
#pragma unroll
  for (int s = 0; s < 4; ++s)
#pragma unroll
    for (int qq = 0; qq < 2; ++qq) {
      int reg = (s < 2) ? s : s - 2;
      int ra = reg * 1024 + qq * 512 + wid * 64;  // wave-uniform chunk base in region
      int idx = ra + lane;
      sR[s][qq] = idx >> 3;
      sC[s][qq] = ((idx & 7) ^ ((idx >> 3) & 7)) * 8;
      sL[s][qq] = ((s < 2) ? 0 : 16384) + ra * 8;  // wave-uniform (+lane*16B by HW)
    }

  // prologue: stage k-tile 0 into buf0 (CUR=1 -> dest buf 0), drain, barrier
  STG(0, 1, 0);
  STG(1, 1, 0);
  STG(2, 1, 0);
  STG(3, 1, 0);
  vwait<0>();
  __builtin_amdgcn_s_barrier();

  const int KT = K >> 6;
  for (int kt = 0; kt < KT - 1; ++kt) {
    const int cur = kt & 1;
    const int k1 = (kt + 1) << 6;
    PH(0, 1, cur, 1, 0, k1, -1);  // B-frags + A0,1 ; stage A-slabs of kt+1
    PH(2, 0, cur, 1, 2, k1, -1);  // A2,3 ; stage B-slabs of kt+1
    PH(4, 0, cur, 0, 0, 0, -1);   // A4,5
    PH(6, 0, cur, 0, 0, 0, 0);    // A6,7 ; drain the 8 prefetch loads (~3 phases old)
  }
  {
    const int cur = (KT - 1) & 1;  // peeled last tile: no staging, nothing outstanding
    PH(0, 1, cur, 0, 0, 0, -1);
    PH(2, 0, cur, 0, 0, 0, -1);
    PH(4, 0, cur, 0, 0, 0, -1);
    PH(6, 0, cur, 0, 0, 0, -1);
  }

#pragma unroll
  for (int i = 0; i < 8; ++i) {
    int m = m0 + wmH * 128 + i * 16 + ((lane >> 4) * 4);
#pragma unroll
    for (int j = 0; j < 4; ++j) {
      int n = n0 + wnq * 64 + j * 16 + l15;
      float bv = (n < 512) ? bias[n] : 0.f;
#pragma unroll
      for (int r = 0; r < 4; ++r) {
        float val = acc[i][j][r] + bv;
        u32 me = (u32)(m + r);
        if (n < 512) {
          fpb[(size_t)me * 512 + n] = f2bf(val);
        } else {
          u32 bdx = me / 196u;
          u32 p = me - bdx * 196u;
          u32 g = (u32)(n - 512) >> 9;
          u32 n9 = (u32)(n - 512) & 511u;
          cnW[(((size_t)bdx * 4 + g) * 196 + p) * 512 + n9] = f2bf(val);
        }
      }
    }
  }
}

// ===== hproj_attn: heterogeneous per step. Blocks 0..127: hWh MFMA GEMM (hp cols 0..2047).
// ===== Blocks 128..191: per-b e+softmax (own VALU hwa; writes albuf[b][196]). 256 thr each.
__global__ __launch_bounds__(256) void hproj_attn(
    const u16* __restrict__ hprev, const u16* __restrict__ wcT, float* __restrict__ hp,
    const u16* __restrict__ fpb, const float* __restrict__ v, float* __restrict__ albuf,
    int t) {
  const int tid = threadIdx.x, lane = tid & 63, wid = tid >> 6;
  if (blockIdx.x < 128) {
    if (t == 0) return;  // h==0: hp unused at t==0 (cell guards on t>0)
    const int ntile = blockIdx.x;
    const int kh = wid;
    const int l15 = lane & 15;
    const u16* Bp = wcT + (size_t)(ntile * 16 + l15) * 512 + kh * 128 + ((lane >> 4) * 8);
    const u16* Ap = hprev + (size_t)l15 * 512 + kh * 128 + ((lane >> 4) * 8);
    f32x4 acc[4] = {};
#pragma unroll
    for (int ks = 0; ks < 4; ++ks) {
      bf16x8 bb = *(const bf16x8*)(Bp + ks * 32);
#pragma unroll
      for (int mf = 0; mf < 4; ++mf) {
        bf16x8 a = *(const bf16x8*)(Ap + (size_t)mf * 16 * 512 + ks * 32);
        acc[mf] = __builtin_amdgcn_mfma_f32_16x16x32_bf16(a, bb, acc[mf], 0, 0, 0);
      }
    }
    __shared__ float pre[4][64][16];
    const int rrow = (lane >> 4) * 4;
#pragma unroll
    for (int mf = 0; mf < 4; ++mf)
#pragma unroll
      for (int r = 0; r < 4; ++r) pre[kh][mf * 16 + rrow + r][l15] = acc[mf][r];
    __syncthreads();
    const int m = tid >> 2, n = (tid & 3) * 4;
    float4 s;
    float* sp = (float*)&s;
#pragma unroll
    for (int j = 0; j < 4; ++j)
      sp[j] = pre[0][m][n + j] + pre[1][m][n + j] + pre[2][m][n + j] + pre[3][m][n + j];
    *(float4*)(hp + (size_t)m * 2560 + ntile * 16 + n) = s;
    return;
  }

  // ---------------- e-block for batch b ----------------
  const int b = blockIdx.x - 128;
  __shared__ float hl[512];
  __shared__ float hwa[512];
  __shared__ float vv[512];
  __shared__ float elds[256];
  __shared__ float sm[16];
  hl[tid] = bf2f(hprev[(size_t)b * 512 + tid]);
  hl[tid + 256] = bf2f(hprev[(size_t)b * 512 + tid + 256]);
  vv[tid] = v[tid];
  vv[tid + 256] = v[tid + 256];
  if (tid >= 196) elds[tid] = -3e38f;
  __syncthreads();
  // hwa[a] = sum_k h[k] * Wa_h[k][a] via wcT rows 2048+a (each thread: a = tid, tid+256)
  {
    float a0 = 0.f, a1 = 0.f;
    if (t > 0) {
      const u16* w0 = wcT + (size_t)(2048 + tid) * 512;
      const u16* w1 = w0 + (size_t)256 * 512;
      for (int k = 0; k < 512; k += 8) {
        bf16x8 wv0 = *(const bf16x8*)(w0 + k);
        bf16x8 wv1 = *(const bf16x8*)(w1 + k);
#pragma unroll
        for (int j = 0; j < 8; ++j) {
          float hk = hl[k + j];
          a0 += hk * bf2f((u16)wv0[j]);
          a1 += hk * bf2f((u16)wv1[j]);
        }
      }
    }
    hwa[tid] = a0;
    hwa[tid + 256] = a1;
  }
  __syncthreads();

  // e[p] = sum_a tanh(fp + hwa) * v  (4 waves, one p per wave per iter)
  float hw[8], vr[8];
#pragma unroll
  for (int j = 0; j < 8; ++j) {
    hw[j] = hwa[lane * 8 + j];
    vr[j] = vv[lane * 8 + j];
  }
  for (int p = wid; p < NP; p += 4) {
    const u16* fp = fpb + ((size_t)b * NP + p) * 512 + lane * 8;
    uint4 raw = *(const uint4*)fp;
    u32 w[4] = {raw.x, raw.y, raw.z, raw.w};
    float part = 0.f;
#pragma unroll
    for (int j = 0; j < 8; ++j) {
      u16 u = (u16)(w[j >> 1] >> ((j & 1) * 16));
      part += tanh_fast(bf2f(u) + hw[j]) * vr[j];
    }
#pragma unroll
    for (int off = 32; off > 0; off >>= 1) part += __shfl_xor(part, off);
    if (lane == 0) elds[p] = part;
  }
  __syncthreads();

  // softmax over 196 (4 waves hold the 256 padded values)
  float ev = elds[tid];
  float m_ = ev;
#pragma unroll
  for (int off = 32; off > 0; off >>= 1) m_ = fmaxf(m_, __shfl_xor(m_, off));
  if (lane == 0) sm[wid] = m_;
  __syncthreads();
  float mx = fmaxf(fmaxf(sm[0], sm[1]), fmaxf(sm[2], sm[3]));
  float w = (tid < NP) ? __builtin_amdgcn_exp2f((ev - mx) * 1.44269504f) : 0.f;
  float s_ = w;
#pragma unroll
  for (int off = 32; off > 0; off >>= 1) s_ += __shfl_xor(s_, off);
  if (lane == 0) sm[8 + wid] = s_;
  __syncthreads();
  if (tid < NP) {
    float tot = (sm[8] + sm[9]) + (sm[10] + sm[11]);
    albuf[(size_t)b * 256 + tid] = w * __builtin_amdgcn_rcpf(tot);
  }
}

// ====== attn_gates: (alpha @ cnnW) + cell, one block per (b, n-quarter). alpha from albuf ======
__global__ __launch_bounds__(1024) void attn_gates(
    const float* __restrict__ albuf, const float* __restrict__ hp, const u16* __restrict__ cw,
    const float* __restrict__ xw, const float* __restrict__ bi, const float* __restrict__ bfg,
    const float* __restrict__ bc, const float* __restrict__ bo, float* __restrict__ cbuf,
    float* __restrict__ out, u16* __restrict__ hnext, int t) {
  const int b = blockIdx.x & 63;
  const int quarter = blockIdx.x >> 6;  // 128 cols of [0,512)
  const int tid = threadIdx.x;
  __shared__ float pre4[512];
  __shared__ float alp[200];
  __shared__ float red[8192];  // partials [4][16][16][8]

  if (tid < NP) alp[tid] = albuf[(size_t)b * 256 + tid];
  __syncthreads();

  // ---- gate pre-activation: pre[g][n'] = sum_p alpha[p]*cnnW[b][g][p][quarter*128+n'] ----
  // 1024 thr = g(4) x pg(16) x colc(16), 8 cols each via uint4.
  {
    const int g = tid >> 8, pg = (tid >> 4) & 15, colc = tid & 15;
    const u16* base = cw + ((size_t)(b * 4 + g) * 196) * 512 + quarter * 128 + colc * 8;
    float acc[8] = {};
    for (int i = 0; i < 13; ++i) {
      int p = pg + i * 16;
      if (p < NP) {
        float al = alp[p];
        uint4 raw = *(const uint4*)(base + (size_t)p * 512);
        u32 wds[4] = {raw.x, raw.y, raw.z, raw.w};
#pragma unroll
        for (int j = 0; j < 8; ++j) acc[j] += al * bf2f((u16)(wds[j >> 1] >> ((j & 1) * 16)));
      }
    }
#pragma unroll
    for (int j = 0; j < 8; ++j) red[((g * 16 + pg) * 16 + colc) * 8 + j] = acc[j];
  }
  __syncthreads();

  // reduce over pg into pre4
  if (tid < 512) {
    const int gg = tid >> 7, nn = tid & 127;
    float s = 0.f;
#pragma unroll
    for (int pg2 = 0; pg2 < 16; ++pg2)
      s += red[((gg * 16 + pg2) * 16 + (nn >> 3)) * 8 + (nn & 7)];
    pre4[gg * 128 + nn] = s;
  }
  __syncthreads();

  // ---- LSTM cell for this quarter's 128 columns ----
  if (tid < 128) {
    const int ng = quarter * 128 + tid;
    const size_t xwo = ((size_t)t * NB + b) * 2048;
    const size_t hpb = (size_t)b * 2560;
    float hwh0 = 0.f, hwh1 = 0.f, hwh2 = 0.f, hwh3 = 0.f;
    if (t > 0) {
      hwh0 = hp[hpb + ng];
      hwh1 = hp[hpb + 512 + ng];
      hwh2 = hp[hpb + 1024 + ng];
      hwh3 = hp[hpb + 1536 + ng];
    }
    float ip = pre4[0 * 128 + tid] + xw[xwo + ng] + hwh0 + bi[ng];
    float fp = pre4[1 * 128 + tid] + xw[xwo + 512 + ng] + hwh1 + bfg[ng];
    float cp = pre4[2 * 128 + tid] + xw[xwo + 1024 + ng] + hwh2 + bc[ng];
    float op = pre4[3 * 128 + tid] + xw[xwo + 1536 + ng] + hwh3 + bo[ng];
    float it = sigmoid_fast(ip), ft = sigmoid_fast(fp), ot = sigmoid_fast(op);
    float ctl = tanh_fast(cp);
    float cold = (t > 0) ? cbuf[(size_t)b * 512 + ng] : 0.f;
    float cn = ft * cold + it * ctl;
    float hn = ot * tanh_fast(cn);
    cbuf[(size_t)b * 512 + ng] = cn;
    hnext[(size_t)b * 512 + ng] = f2bf(hn);
    out[((size_t)b * NT + t) * 512 + ng] = hn;
    if (t == NT - 1) {
      out[(size_t)NB * NT * 512 + (size_t)b * 512 + ng] = hn;
      out[(size_t)NB * NT * 512 + (size_t)NB * 512 + (size_t)b * 512 + ng] = cn;
    }
  }
}

// ======================= host launcher =======================
extern "C" void kernel_launch(void* const* d_in, const int* in_sizes, int n_in, void* d_out,
                              int out_size, void* d_ws, size_t ws_size, hipStream_t stream) {
  const float* x = (const float*)d_in[0];
  const float* cnn = (const float*)d_in[1];
  const float* Wi = (const float*)d_in[2];
  const float* bi = (const float*)d_in[3];
  const float* Wf = (const float*)d_in[4];
  const float* bfv = (const float*)d_in[5];
  const float* Wc = (const float*)d_in[6];
  const float* bc = (const float*)d_in[7];
  const float* Wo = (const float*)d_in[8];
  const float* bo = (const float*)d_in[9];
  const float* Waf = (const float*)d_in[10];
  const float* Wah = (const float*)d_in[11];
  const float* ba = (const float*)d_in[12];
  const float* v = (const float*)d_in[13];
  float* out = (float*)d_out;

  char* base = (char*)d_ws;
  size_t off = 0;
  auto alloc = [&](size_t bytes) {
    char* r = base + off;
    off += (bytes + 255) & ~(size_t)255;
    return r;
  };
  u16* cnnb = (u16*)alloc((size_t)NB * NP * NE * 2);      // 51.4 MB
  u16* fpb = (u16*)alloc((size_t)NB * NP * NA * 2);       // 12.8 MB
  u16* cnW = (u16*)alloc((size_t)NB * 4 * NP * 512 * 2);  // 51.4 MB [b][g][p][n']
  u16* wbig = (u16*)alloc((size_t)2560 * 2048 * 2);       // 10.5 MB [512 Wa_feat^T | 2048 Wctx^T]
  u16* wcombT = (u16*)alloc((size_t)2560 * 512 * 2);      // 2.6 MB  [2048 hWh | 512 hWa][512]
  u16* wxt = (u16*)alloc((size_t)4 * 512 * 512 * 2);      // 2 MB
  u16* xbT = (u16*)alloc((size_t)NT * NB * 512 * 2);      // 1.3 MB  [t][b][512]
  float* xw = (float*)alloc((size_t)NT * NB * 2048 * 4);  // 10.5 MB [t][b][2048]
  u16* hbuf = (u16*)alloc((size_t)2 * NB * 512 * 2);      // 128 KB (double buffer)
  float* cbuf = (float*)alloc((size_t)NB * 512 * 4);      // 128 KB
  float* hp = (float*)alloc((size_t)NB * 2560 * 4);       // 656 KB [b][hWh 2048 | (unused 512)]
  float* albuf = (float*)alloc((size_t)NB * 256 * 4);     // 64 KB  alpha per b

  (void)ws_size;
  (void)in_sizes;
  (void)n_in;
  (void)out_size;

  // all preprocessing in one launch
  prep_all<<<10112, 256, 0, stream>>>((const float4*)cnn, x, Wi, Wf, Wc, Wo, Waf, Wah, cnnb, xbT,
                                      wxt, wbig, wcombT);

  // merged: [fpb | cnW] = cnnb @ [Wa_feat^T | Wctx^T]  (M=12544, N=2560, K=2048)
  gemm256<<<49 * 10, 512, 0, stream>>>(cnnb, wbig, ba, fpb, cnW, 2048, 10);

  // xw = xT @ W[:512,:] (4 gates) -> f32 [t*64+b][2048]
  {
    dim3 g(1280 / 128, 2048 / 128);
    gemm_bf16<<<g, 256, 0, stream>>>(xbT, wxt, xw, 1280, 2048, 512);
  }

  // 20-step recurrence: hproj_attn (hWh GEMM || per-b e+softmax) + attn_gates
  for (int t = 0; t < NT; ++t) {
    const u16* hprev = hbuf + (size_t)(t & 1) * NB * 512;
    u16* hnext = hbuf + (size_t)((t + 1) & 1) * NB * 512;
    hproj_attn<<<192, 256, 0, stream>>>(hprev, wcombT, hp, fpb, v, albuf, t);
    attn_gates<<<256, 1024, 0, stream>>>(albuf, hp, cnW, xw, bi, bfv, bc, bo, cbuf, out, hnext,
                                         t);
  }
}

// Round 17
// 667.490 us; speedup vs baseline: 2.0091x; 2.0091x over previous
//
#include <hip/hip_runtime.h>

typedef unsigned short u16;
typedef unsigned int u32;
typedef __attribute__((ext_vector_type(8))) short bf16x8;
typedef __attribute__((ext_vector_type(4))) float f32x4;

// B=64 T=20 D_IN=512 H=512 D_ENC=2048 P=196 D_ATT=512
#define NB 64
#define NT 20
#define NH 512
#define NP 196
#define NE 2048
#define NA 512

__device__ __forceinline__ u16 f2bf(float f) {
  u32 b = __float_as_uint(f);
  return (u16)((b + 0x7FFFu + ((b >> 16) & 1u)) >> 16);
}
__device__ __forceinline__ float bf2f(u16 u) { return __uint_as_float(((u32)u) << 16); }
__device__ __forceinline__ float tanh_fast(float x) {
  float xc = fminf(fmaxf(x, -15.f), 15.f);
  float e2 = __builtin_amdgcn_exp2f(xc * 2.885390082f);
  return (e2 - 1.f) * __builtin_amdgcn_rcpf(e2 + 1.f);
}
__device__ __forceinline__ float sigmoid_fast(float x) {
  return __builtin_amdgcn_rcpf(1.f + __builtin_amdgcn_exp2f(x * -1.44269504f));
}

__device__ __forceinline__ void gload_lds16(const u16* g, u16* l) {
  __builtin_amdgcn_global_load_lds((const __attribute__((address_space(1))) void*)g,
                                   (__attribute__((address_space(3))) void*)l, 16, 0, 0);
}

template <int N>
__device__ __forceinline__ void vwait() {
  if constexpr (N >= 0)
    asm volatile("s_waitcnt vmcnt(%0)" ::"i"(N) : "memory");
  else
    asm volatile("" ::: "memory");
}

// ---------------- f32 -> bf16 convert (vectorized, grid-stride) ----------------
__global__ __launch_bounds__(256) void conv_bf16(const float4* __restrict__ src,
                                                 u16* __restrict__ dst, int n4) {
  int i = blockIdx.x * 256 + threadIdx.x;
  int stride = gridDim.x * 256;
  for (; i < n4; i += stride) {
    float4 v = src[i];
    u32 lo = (u32)f2bf(v.x) | ((u32)f2bf(v.y) << 16);
    u32 hi = (u32)f2bf(v.z) | ((u32)f2bf(v.w) << 16);
    *(uint2*)(dst + (size_t)i * 4) = make_uint2(lo, hi);
  }
}

// ---------------- x [b][t][512] f32 -> xbT [t][b][512] bf16 ----------------
__global__ __launch_bounds__(128) void conv_x(const float* __restrict__ x,
                                              u16* __restrict__ xbT) {
  int b = blockIdx.x, t = blockIdx.y, tid = threadIdx.x;
  float4 v = *(const float4*)(x + ((size_t)b * NT + t) * 512 + tid * 4);
  u32 lo = (u32)f2bf(v.x) | ((u32)f2bf(v.y) << 16);
  u32 hi = (u32)f2bf(v.z) | ((u32)f2bf(v.w) << 16);
  *(uint2*)(xbT + ((size_t)t * NB + b) * 512 + tid * 4) = make_uint2(lo, hi);
}

// ------- ALL weight transposes in ONE launch: f32 [K][512](+row_off) -> bf16 [n][K] -------
// Job table (flattened blockIdx.x):
//   J0 [0,1024):    wxt    (Wi..Wo z=0..3, row_off 0,    K 512,  16x16 tiles)
//   J1 [1024,2048): wbig   (Waf,          row_off 0,    K 2048, 64x16)
//   J2 [2048,6144): wbig+  (Wi..Wo z=0..3, row_off 1024, K 2048, 64x16)
//   J3 [6144,7168): wcombT (Wi..Wo z=0..3, row_off 512,  K 512,  16x16)
//   J4 [7168,7424): wcombT+(Wah,          row_off 0,    K 512,  16x16)
__global__ __launch_bounds__(256) void transpose_all(
    const float* __restrict__ Wi, const float* __restrict__ Wf, const float* __restrict__ Wc,
    const float* __restrict__ Wo, const float* __restrict__ Waf, const float* __restrict__ Wah,
    u16* __restrict__ wxt, u16* __restrict__ wbig, u16* __restrict__ wcombT) {
  const int blk = blockIdx.x;
  const float* src;
  u16* dst;
  int row_off, K, bx, by;
  if (blk < 1024) {
    int z = blk >> 8, r = blk & 255;
    bx = r & 15;
    by = r >> 4;
    src = z == 0 ? Wi : z == 1 ? Wf : z == 2 ? Wc : Wo;
    dst = wxt + (size_t)z * 512 * 512;
    row_off = 0;
    K = 512;
  } else if (blk < 2048) {
    int r = blk - 1024;
    bx = r & 63;
    by = r >> 6;
    src = Waf;
    dst = wbig;
    row_off = 0;
    K = 2048;
  } else if (blk < 6144) {
    int r = blk - 2048;
    int z = r >> 10, r2 = r & 1023;
    bx = r2 & 63;
    by = r2 >> 6;
    src = z == 0 ? Wi : z == 1 ? Wf : z == 2 ? Wc : Wo;
    dst = wbig + (size_t)512 * 2048 + (size_t)z * 512 * 2048;
    row_off = 1024;
    K = 2048;
  } else if (blk < 7168) {
    int r = blk - 6144;
    int z = r >> 8, r2 = r & 255;
    bx = r2 & 15;
    by = r2 >> 4;
    src = z == 0 ? Wi : z == 1 ? Wf : z == 2 ? Wc : Wo;
    dst = wcombT + (size_t)z * 512 * 512;
    row_off = 512;
    K = 512;
  } else {
    int r = blk - 7168;
    bx = r & 15;
    by = r >> 4;
    src = Wah;
    dst = wcombT + (size_t)2048 * 512;
    row_off = 0;
    K = 512;
  }
  __shared__ float tile[32][33];
  const int k0 = bx * 32, n0 = by * 32;
  const int tx = threadIdx.x & 31, ty = threadIdx.x >> 5;  // 32 x 8
#pragma unroll
  for (int i = 0; i < 4; ++i)
    tile[ty + i * 8][tx] = src[(size_t)(row_off + k0 + ty + i * 8) * 512 + n0 + tx];
  __syncthreads();
#pragma unroll
  for (int i = 0; i < 4; ++i) {
    int n = n0 + ty + i * 8, k = k0 + tx;
    dst[(size_t)n * K + k] = f2bf(tile[tx][ty + i * 8]);
  }
}

// ------------- 128^2 bf16 MFMA GEMM (global_load_lds staging), f32 out: xw -------------
__global__ __launch_bounds__(256) void gemm_bf16(const u16* __restrict__ A,
                                                 const u16* __restrict__ BT,
                                                 float* __restrict__ C, int M, int N, int K) {
  __shared__ u16 lA[128 * 64];
  __shared__ u16 lB[128 * 64];
  const int tid = threadIdx.x;
  const int lane = tid & 63;
  const int wid = tid >> 6;
  const int m0 = blockIdx.x * 128, n0 = blockIdx.y * 128;
  const int wm = (wid >> 1) * 64, wn = (wid & 1) * 64;
  f32x4 acc[4][4] = {};

  const int cbase = wid * 256;  // wave-uniform
  int srcr[4], srcc[4];
#pragma unroll
  for (int it = 0; it < 4; ++it) {
    int c = cbase + it * 64 + lane;
    srcr[it] = c >> 3;
    srcc[it] = ((c & 7) ^ ((c >> 3) & 7)) * 8;
  }

  for (int k0 = 0; k0 < K; k0 += 64) {
    __syncthreads();
#pragma unroll
    for (int it = 0; it < 4; ++it) {
      gload_lds16(A + (size_t)(m0 + srcr[it]) * K + k0 + srcc[it],
                  lA + (size_t)(cbase + it * 64) * 8);
      gload_lds16(BT + (size_t)(n0 + srcr[it]) * K + k0 + srcc[it],
                  lB + (size_t)(cbase + it * 64) * 8);
    }
    __syncthreads();
#pragma unroll
    for (int kk = 0; kk < 2; ++kk) {
      int kchunk = kk * 4 + (lane >> 4);
      bf16x8 af[4], bg[4];
#pragma unroll
      for (int i = 0; i < 4; ++i) {
        int row = wm + i * 16 + (lane & 15);
        af[i] = *(const bf16x8*)(lA + row * 64 + ((kchunk ^ (row & 7)) * 8));
        int rowb = wn + i * 16 + (lane & 15);
        bg[i] = *(const bf16x8*)(lB + rowb * 64 + ((kchunk ^ (rowb & 7)) * 8));
      }
#pragma unroll
      for (int i = 0; i < 4; ++i)
#pragma unroll
        for (int j = 0; j < 4; ++j)
          acc[i][j] = __builtin_amdgcn_mfma_f32_16x16x32_bf16(af[i], bg[j], acc[i][j], 0, 0, 0);
    }
  }
#pragma unroll
  for (int i = 0; i < 4; ++i) {
    int m = m0 + wm + i * 16 + ((lane >> 4) * 4);
#pragma unroll
    for (int j = 0; j < 4; ++j) {
      int n = n0 + wn + j * 16 + (lane & 15);
#pragma unroll
      for (int r = 0; r < 4; ++r) C[(size_t)(m + r) * N + n] = acc[i][j][r];
    }
  }
}

// ------- 256^2 bf16 MFMA GEMM (R11 version): wave owns 128x64, double-buffered LDS -------
// 512 thr = 8 waves (2 A-halves x 4 B-quarters). Per K-tile: 4 phases x 16 MFMA.
// ph0 reads all 8 B-frags (carried in regs) + A0,1; ph1-3 read A-frag pairs.
// ph0 stages A-slabs of kt+1, ph1 B-slabs; vmcnt(0) at ph3 (~3 phases of slack).
#define STG(SS, CUR, K1)                                                                    \
  do {                                                                                      \
    _Pragma("unroll") for (int q_ = 0; q_ < 2; ++q_) {                                      \
      const u16* g_ = ((SS) < 2)                                                            \
                          ? (A + (size_t)(m0 + sR[SS][q_]) * K + (K1) + sC[SS][q_])         \
                          : (BT + (size_t)(n0 + sR[SS][q_]) * K + (K1) + sC[SS][q_]);       \
      gload_lds16(g_, lds + ((CUR) ^ 1) * 32768 + sL[SS][q_]);                              \
    }                                                                                       \
  } while (0)

#define PH(MF0, READB, CUR, DOSTAGE, SB, K1, WN)                                            \
  do {                                                                                      \
    const u16* pA_ = lds + (CUR) * 32768;                                                   \
    const u16* pB_ = pA_ + 16384;                                                           \
    bf16x8 af_[2][2];                                                                       \
    _Pragma("unroll") for (int kh_ = 0; kh_ < 2; ++kh_) {                                   \
      const int kc_ = kh_ * 4 + (lane >> 4);                                                \
      _Pragma("unroll") for (int ii_ = 0; ii_ < 2; ++ii_) {                                 \
        const int rA_ = wmH * 128 + ((MF0) + ii_) * 16 + l15;                               \
        af_[kh_][ii_] = *(const bf16x8*)(pA_ + rA_ * 64 + ((kc_ ^ (rA_ & 7)) * 8));         \
      }                                                                                     \
      if (READB) {                                                                          \
        _Pragma("unroll") for (int j_ = 0; j_ < 4; ++j_) {                                  \
          const int rB_ = wnq * 64 + j_ * 16 + l15;                                         \
          bg[kh_][j_] = *(const bf16x8*)(pB_ + rB_ * 64 + ((kc_ ^ (rB_ & 7)) * 8));         \
        }                                                                                   \
      }                                                                                     \
    }                                                                                       \
    if (DOSTAGE) {                                                                          \
      STG(SB, CUR, K1);                                                                     \
      STG((SB) + 1, CUR, K1);                                                               \
    }                                                                                       \
    vwait<WN>();                                                                            \
    __builtin_amdgcn_s_barrier();                                                           \
    __builtin_amdgcn_s_setprio(1);                                                          \
    _Pragma("unroll") for (int kh_ = 0; kh_ < 2; ++kh_)                                     \
      _Pragma("unroll") for (int ii_ = 0; ii_ < 2; ++ii_)                                   \
        _Pragma("unroll") for (int j_ = 0; j_ < 4; ++j_)                                    \
          acc[(MF0) + ii_][j_] = __builtin_amdgcn_mfma_f32_16x16x32_bf16(                   \
              af_[kh_][ii_], bg[kh_][j_], acc[(MF0) + ii_][j_], 0, 0, 0);                   \
    __builtin_amdgcn_s_setprio(0);                                                          \
    __builtin_amdgcn_s_barrier();                                                           \
  } while (0)

__global__ __launch_bounds__(512, 2) void gemm256(const u16* __restrict__ A,
                                                  const u16* __restrict__ BT,
                                                  const float* __restrict__ bias,
                                                  u16* __restrict__ fpb, u16* __restrict__ cnW,
                                                  int K, int grid_n) {
  __shared__ u16 lds[65536];  // [buf][A 256x64 | B 256x64] u16 = 128 KiB
  const int tid = threadIdx.x;
  const int lane = tid & 63;
  const int wid = tid >> 6;
  const int l15 = lane & 15;
  // bijective XCD-chunked swizzle (m204)
  const int nblk = gridDim.x;
  const int q = nblk >> 3, rr = nblk & 7;
  const int xcd = blockIdx.x & 7, jj = blockIdx.x >> 3;
  const int swz = (xcd < rr ? xcd * (q + 1) : rr * (q + 1) + (xcd - rr) * q) + jj;
  const int mt = swz / grid_n, nt = swz - mt * grid_n;
  const int m0 = mt * 256, n0 = nt * 256;
  const int wmH = wid >> 2;  // A-half (0/1): rows wmH*128..+128
  const int wnq = wid & 3;   // B quarter: cols wnq*64..+64
  f32x4 acc[8][4] = {};
  bf16x8 bg[2][4];  // B-frags read once per K-tile (ph0), carried through ph1-3

  // staging geometry: slab s (1024 chunks of 16B): 0,1 = A rows 0-127 / 128-255;
  // 2,3 = B rows 0-127 / 128-255. Each slab = 2 chunks/thread (q=0,1).
  int sR[4][2], sC[4][2], sL[4][2];
#pragma unroll
  for (int s = 0; s < 4; ++s)
#pragma unroll
    for (int qq = 0; qq < 2; ++qq) {
      int reg = (s < 2) ? s : s - 2;
      int ra = reg * 1024 + qq * 512 + wid * 64;  // wave-uniform chunk base in region
      int idx = ra + lane;
      sR[s][qq] = idx >> 3;
      sC[s][qq] = ((idx & 7) ^ ((idx >> 3) & 7)) * 8;
      sL[s][qq] = ((s < 2) ? 0 : 16384) + ra * 8;  // wave-uniform (+lane*16B by HW)
    }

  // prologue: stage k-tile 0 into buf0 (CUR=1 -> dest buf 0), drain, barrier
  STG(0, 1, 0);
  STG(1, 1, 0);
  STG(2, 1, 0);
  STG(3, 1, 0);
  vwait<0>();
  __builtin_amdgcn_s_barrier();

  const int KT = K >> 6;
  for (int kt = 0; kt < KT - 1; ++kt) {
    const int cur = kt & 1;
    const int k1 = (kt + 1) << 6;
    PH(0, 1, cur, 1, 0, k1, -1);  // B-frags + A0,1 ; stage A-slabs of kt+1
    PH(2, 0, cur, 1, 2, k1, -1);  // A2,3 ; stage B-slabs of kt+1
    PH(4, 0, cur, 0, 0, 0, -1);   // A4,5
    PH(6, 0, cur, 0, 0, 0, 0);    // A6,7 ; drain the 8 prefetch loads (~3 phases old)
  }
  {
    const int cur = (KT - 1) & 1;  // peeled last tile: no staging, nothing outstanding
    PH(0, 1, cur, 0, 0, 0, -1);
    PH(2, 0, cur, 0, 0, 0, -1);
    PH(4, 0, cur, 0, 0, 0, -1);
    PH(6, 0, cur, 0, 0, 0, -1);
  }

#pragma unroll
  for (int i = 0; i < 8; ++i) {
    int m = m0 + wmH * 128 + i * 16 + ((lane >> 4) * 4);
#pragma unroll
    for (int j = 0; j < 4; ++j) {
      int n = n0 + wnq * 64 + j * 16 + l15;
      float bv = (n < 512) ? bias[n] : 0.f;
#pragma unroll
      for (int r = 0; r < 4; ++r) {
        float val = acc[i][j][r] + bv;
        u32 me = (u32)(m + r);
        if (n < 512) {
          fpb[(size_t)me * 512 + n] = f2bf(val);
        } else {
          u32 bdx = me / 196u;
          u32 p = me - bdx * 196u;
          u32 g = (u32)(n - 512) >> 9;
          u32 n9 = (u32)(n - 512) & 511u;
          cnW[(((size_t)bdx * 4 + g) * 196 + p) * 512 + n9] = f2bf(val);
        }
      }
    }
  }
}

// ---------------- hproj: hp[64][2560] = h[64][512] @ wcT[2560][512]^T (f32 out) ----------------
__global__ __launch_bounds__(256) void hproj(const u16* __restrict__ hprev,
                                             const u16* __restrict__ wcT,
                                             float* __restrict__ hp) {
  const int ntile = blockIdx.x;
  const int tid = threadIdx.x, lane = tid & 63, kh = tid >> 6;
  const int l15 = lane & 15;
  const u16* Bp = wcT + (size_t)(ntile * 16 + l15) * 512 + kh * 128 + ((lane >> 4) * 8);
  const u16* Ap = hprev + (size_t)l15 * 512 + kh * 128 + ((lane >> 4) * 8);
  f32x4 acc[4] = {};
#pragma unroll
  for (int ks = 0; ks < 4; ++ks) {
    bf16x8 bb = *(const bf16x8*)(Bp + ks * 32);
#pragma unroll
    for (int mf = 0; mf < 4; ++mf) {
      bf16x8 a = *(const bf16x8*)(Ap + (size_t)mf * 16 * 512 + ks * 32);
      acc[mf] = __builtin_amdgcn_mfma_f32_16x16x32_bf16(a, bb, acc[mf], 0, 0, 0);
    }
  }
  __shared__ float pre[4][64][16];
  const int rrow = (lane >> 4) * 4;
#pragma unroll
  for (int mf = 0; mf < 4; ++mf)
#pragma unroll
    for (int r = 0; r < 4; ++r) pre[kh][mf * 16 + rrow + r][l15] = acc[mf][r];
  __syncthreads();
  const int m = tid >> 2, n = (tid & 3) * 4;
  float4 s;
  float* sp = (float*)&s;
#pragma unroll
  for (int j = 0; j < 4; ++j)
    sp[j] = pre[0][m][n + j] + pre[1][m][n + j] + pre[2][m][n + j] + pre[3][m][n + j];
  *(float4*)(hp + (size_t)m * 2560 + ntile * 16 + n) = s;
}

// ====== attn_gates: e + softmax + (alpha @ cnnW) + cell, one block per (b, n-quarter) ======
// grid 256: b = blk & 63, quarter = blk >> 6 (all 4 quarter-blocks of b share an XCD L2).
__global__ __launch_bounds__(1024) void attn_gates(
    const u16* __restrict__ fpb, const float* __restrict__ hp, const float* __restrict__ v,
    const u16* __restrict__ cw, const float* __restrict__ xw, const float* __restrict__ bi,
    const float* __restrict__ bfg, const float* __restrict__ bc, const float* __restrict__ bo,
    float* __restrict__ cbuf, float* __restrict__ out, u16* __restrict__ hnext, int t) {
  const int b = blockIdx.x & 63;
  const int quarter = blockIdx.x >> 6;  // 128 cols of [0,512)
  const int tid = threadIdx.x;
  const int lane = tid & 63, wid = tid >> 6;
  __shared__ float smem_a[1024];  // [0..511] hwa, [512..1023] vv; later pre4[4][128]
  __shared__ float sm[16];
  __shared__ float alp[200];
  __shared__ float red[8192];  // e[] in [0..255] first, then partials [4][16][16][8]

  float* hwa = smem_a;
  float* vv = smem_a + 512;
  if (tid < 512) {
    hwa[tid] = (t > 0) ? hp[(size_t)b * 2560 + 2048 + tid] : 0.f;
    vv[tid] = v[tid];
  }
  if (tid >= 196 && tid < 256) red[tid] = -3e38f;
  __syncthreads();

  // ---- e[p] = sum_a tanh(fp + hwa) * v ----
  float hw[8], vr[8];
#pragma unroll
  for (int j = 0; j < 8; ++j) {
    hw[j] = hwa[lane * 8 + j];
    vr[j] = vv[lane * 8 + j];
  }
  for (int p = wid; p < NP; p += 16) {
    const u16* fp = fpb + ((size_t)b * NP + p) * 512 + lane * 8;
    uint4 raw = *(const uint4*)fp;
    u32 w[4] = {raw.x, raw.y, raw.z, raw.w};
    float part = 0.f;
#pragma unroll
    for (int j = 0; j < 8; ++j) {
      u16 u = (u16)(w[j >> 1] >> ((j & 1) * 16));
      part += tanh_fast(bf2f(u) + hw[j]) * vr[j];
    }
#pragma unroll
    for (int off = 32; off > 0; off >>= 1) part += __shfl_xor(part, off);
    if (lane == 0) red[p] = part;
  }
  __syncthreads();

  // ---- softmax over 196: wave-level reduce (4 waves hold the 256 padded e-values) ----
  float ev = 0.f, w = 0.f;
  if (tid < 256) {
    ev = red[tid];
    float m_ = ev;
#pragma unroll
    for (int off = 32; off > 0; off >>= 1) m_ = fmaxf(m_, __shfl_xor(m_, off));
    if (lane == 0) sm[wid] = m_;
  }
  __syncthreads();
  if (tid < 256) {
    float mx = fmaxf(fmaxf(sm[0], sm[1]), fmaxf(sm[2], sm[3]));
    w = (tid < NP) ? __builtin_amdgcn_exp2f((ev - mx) * 1.44269504f) : 0.f;
    float s_ = w;
#pragma unroll
    for (int off = 32; off > 0; off >>= 1) s_ += __shfl_xor(s_, off);
    if (lane == 0) sm[8 + wid] = s_;
  }
  __syncthreads();
  if (tid < NP) {
    float tot = (sm[8] + sm[9]) + (sm[10] + sm[11]);
    alp[tid] = w * __builtin_amdgcn_rcpf(tot);
  }
  __syncthreads();

  // ---- gate pre-activation: pre[g][n'] = sum_p alpha[p]*cnnW[b][g][p][quarter*128+n'] ----
  // 1024 thr = g(4) x pg(16) x colc(16), 8 cols each via uint4.
  {
    const int g = tid >> 8, pg = (tid >> 4) & 15, colc = tid & 15;
    const u16* base = cw + ((size_t)(b * 4 + g) * 196) * 512 + quarter * 128 + colc * 8;
    float acc[8] = {};
    for (int i = 0; i < 13; ++i) {
      int p = pg + i * 16;
      if (p < NP) {
        float al = alp[p];
        uint4 raw = *(const uint4*)(base + (size_t)p * 512);
        u32 wds[4] = {raw.x, raw.y, raw.z, raw.w};
#pragma unroll
        for (int j = 0; j < 8; ++j) acc[j] += al * bf2f((u16)(wds[j >> 1] >> ((j & 1) * 16)));
      }
    }
#pragma unroll
    for (int j = 0; j < 8; ++j) red[((g * 16 + pg) * 16 + colc) * 8 + j] = acc[j];
  }
  __syncthreads();

  // reduce over pg into pre4 (aliases smem_a)
  float* pre4 = smem_a;
  if (tid < 512) {
    const int gg = tid >> 7, nn = tid & 127;
    float s = 0.f;
#pragma unroll
    for (int pg2 = 0; pg2 < 16; ++pg2)
      s += red[((gg * 16 + pg2) * 16 + (nn >> 3)) * 8 + (nn & 7)];
    pre4[gg * 128 + nn] = s;
  }
  __syncthreads();

  // ---- LSTM cell for this quarter's 128 columns ----
  if (tid < 128) {
    const int ng = quarter * 128 + tid;
    const size_t xwo = ((size_t)t * NB + b) * 2048;
    const size_t hpb = (size_t)b * 2560;
    float hwh0 = 0.f, hwh1 = 0.f, hwh2 = 0.f, hwh3 = 0.f;
    if (t > 0) {
      hwh0 = hp[hpb + ng];
      hwh1 = hp[hpb + 512 + ng];
      hwh2 = hp[hpb + 1024 + ng];
      hwh3 = hp[hpb + 1536 + ng];
    }
    float ip = pre4[0 * 128 + tid] + xw[xwo + ng] + hwh0 + bi[ng];
    float fp = pre4[1 * 128 + tid] + xw[xwo + 512 + ng] + hwh1 + bfg[ng];
    float cp = pre4[2 * 128 + tid] + xw[xwo + 1024 + ng] + hwh2 + bc[ng];
    float op = pre4[3 * 128 + tid] + xw[xwo + 1536 + ng] + hwh3 + bo[ng];
    float it = sigmoid_fast(ip), ft = sigmoid_fast(fp), ot = sigmoid_fast(op);
    float ctl = tanh_fast(cp);
    float cold = (t > 0) ? cbuf[(size_t)b * 512 + ng] : 0.f;
    float cn = ft * cold + it * ctl;
    float hn = ot * tanh_fast(cn);
    cbuf[(size_t)b * 512 + ng] = cn;
    hnext[(size_t)b * 512 + ng] = f2bf(hn);
    out[((size_t)b * NT + t) * 512 + ng] = hn;
    if (t == NT - 1) {
      out[(size_t)NB * NT * 512 + (size_t)b * 512 + ng] = hn;
      out[(size_t)NB * NT * 512 + (size_t)NB * 512 + (size_t)b * 512 + ng] = cn;
    }
  }
}

// ======================= host launcher =======================
extern "C" void kernel_launch(void* const* d_in, const int* in_sizes, int n_in, void* d_out,
                              int out_size, void* d_ws, size_t ws_size, hipStream_t stream) {
  const float* x = (const float*)d_in[0];
  const float* cnn = (const float*)d_in[1];
  const float* Wi = (const float*)d_in[2];
  const float* bi = (const float*)d_in[3];
  const float* Wf = (const float*)d_in[4];
  const float* bfv = (const float*)d_in[5];
  const float* Wc = (const float*)d_in[6];
  const float* bc = (const float*)d_in[7];
  const float* Wo = (const float*)d_in[8];
  const float* bo = (const float*)d_in[9];
  const float* Waf = (const float*)d_in[10];
  const float* Wah = (const float*)d_in[11];
  const float* ba = (const float*)d_in[12];
  const float* v = (const float*)d_in[13];
  float* out = (float*)d_out;

  char* base = (char*)d_ws;
  size_t off = 0;
  auto alloc = [&](size_t bytes) {
    char* r = base + off;
    off += (bytes + 255) & ~(size_t)255;
    return r;
  };
  u16* cnnb = (u16*)alloc((size_t)NB * NP * NE * 2);      // 51.4 MB
  u16* fpb = (u16*)alloc((size_t)NB * NP * NA * 2);       // 12.8 MB
  u16* cnW = (u16*)alloc((size_t)NB * 4 * NP * 512 * 2);  // 51.4 MB [b][g][p][n']
  u16* wbig = (u16*)alloc((size_t)2560 * 2048 * 2);       // 10.5 MB [512 Wa_feat^T | 2048 Wctx^T]
  u16* wcombT = (u16*)alloc((size_t)2560 * 512 * 2);      // 2.6 MB  [2048 hWh | 512 hWa][512]
  u16* wxt = (u16*)alloc((size_t)4 * 512 * 512 * 2);      // 2 MB
  u16* xbT = (u16*)alloc((size_t)NT * NB * 512 * 2);      // 1.3 MB  [t][b][512]
  float* xw = (float*)alloc((size_t)NT * NB * 2048 * 4);  // 10.5 MB [t][b][2048]
  u16* hbuf = (u16*)alloc((size_t)2 * NB * 512 * 2);      // 128 KB (double buffer)
  float* cbuf = (float*)alloc((size_t)NB * 512 * 4);      // 128 KB
  float* hp = (float*)alloc((size_t)NB * 2560 * 4);       // 656 KB [b][hWh 2048 | hWa 512]

  (void)ws_size;
  (void)in_sizes;
  (void)n_in;
  (void)out_size;

  // conversions / transposes (all transposes in one launch)
  conv_bf16<<<2048, 256, 0, stream>>>((const float4*)cnn, cnnb, (NB * NP * NE) / 4);
  conv_x<<<dim3(NB, NT), 128, 0, stream>>>(x, xbT);
  transpose_all<<<7424, 256, 0, stream>>>(Wi, Wf, Wc, Wo, Waf, Wah, wxt, wbig, wcombT);

  // merged: [fpb | cnW] = cnnb @ [Wa_feat^T | Wctx^T]  (M=12544, N=2560, K=2048)
  gemm256<<<49 * 10, 512, 0, stream>>>(cnnb, wbig, ba, fpb, cnW, 2048, 10);

  // xw = xT @ W[:512,:] (4 gates) -> f32 [t*64+b][2048]
  {
    dim3 g(1280 / 128, 2048 / 128);
    gemm_bf16<<<g, 256, 0, stream>>>(xbT, wxt, xw, 1280, 2048, 512);
  }

  // 20-step recurrence: hproj (t>0) + fused attn/gates
  for (int t = 0; t < NT; ++t) {
    const u16* hprev = hbuf + (size_t)(t & 1) * NB * 512;
    u16* hnext = hbuf + (size_t)((t + 1) & 1) * NB * 512;
    if (t > 0) hproj<<<160, 256, 0, stream>>>(hprev, wcombT, hp);
    attn_gates<<<256, 1024, 0, stream>>>(fpb, hp, v, cnW, xw, bi, bfv, bc, bo, cbuf, out, hnext,
                                         t);
  }
}

// Round 18
// 662.147 us; speedup vs baseline: 2.0253x; 1.0081x over previous
//
#include <hip/hip_runtime.h>

typedef unsigned short u16;
typedef unsigned int u32;
typedef __attribute__((ext_vector_type(8))) short bf16x8;
typedef __attribute__((ext_vector_type(4))) float f32x4;

// B=64 T=20 D_IN=512 H=512 D_ENC=2048 P=196 D_ATT=512
#define NB 64
#define NT 20
#define NH 512
#define NP 196
#define NE 2048
#define NA 512

__device__ __forceinline__ u16 f2bf(float f) {
  u32 b = __float_as_uint(f);
  return (u16)((b + 0x7FFFu + ((b >> 16) & 1u)) >> 16);
}
__device__ __forceinline__ float bf2f(u16 u) { return __uint_as_float(((u32)u) << 16); }
__device__ __forceinline__ float tanh_fast(float x) {
  float xc = fminf(fmaxf(x, -15.f), 15.f);
  float e2 = __builtin_amdgcn_exp2f(xc * 2.885390082f);
  return (e2 - 1.f) * __builtin_amdgcn_rcpf(e2 + 1.f);
}
__device__ __forceinline__ float sigmoid_fast(float x) {
  return __builtin_amdgcn_rcpf(1.f + __builtin_amdgcn_exp2f(x * -1.44269504f));
}

__device__ __forceinline__ void gload_lds16(const u16* g, u16* l) {
  __builtin_amdgcn_global_load_lds((const __attribute__((address_space(1))) void*)g,
                                   (__attribute__((address_space(3))) void*)l, 16, 0, 0);
}

template <int N>
__device__ __forceinline__ void vwait() {
  if constexpr (N >= 0)
    asm volatile("s_waitcnt vmcnt(%0)" ::"i"(N) : "memory");
  else
    asm volatile("" ::: "memory");
}

// ===== prep_all: cnn->bf16 (J0), x->xbT (J1), all weight transposes (J2..) in ONE launch =====
// J0 [0,2048):         conv cnn (grid-stride over 6422528 float4)
// J1 [2048,2688):      conv_x   (163840 float4, 1 per thread)
// J2 [2688,2688+7424): transposes (job table = R15 transpose_all)
__global__ __launch_bounds__(256) void prep_all(
    const float4* __restrict__ cnn4, const float* __restrict__ x, const float* __restrict__ Wi,
    const float* __restrict__ Wf, const float* __restrict__ Wc, const float* __restrict__ Wo,
    const float* __restrict__ Waf, const float* __restrict__ Wah, u16* __restrict__ cnnb,
    u16* __restrict__ xbT, u16* __restrict__ wxt, u16* __restrict__ wbig,
    u16* __restrict__ wcombT) {
  const int blk = blockIdx.x, tid = threadIdx.x;
  __shared__ float tile[32][33];
  if (blk < 2048) {
    const int n4 = (NB * NP * NE) / 4;
    for (int i = blk * 256 + tid; i < n4; i += 2048 * 256) {
      float4 v = cnn4[i];
      u32 lo = (u32)f2bf(v.x) | ((u32)f2bf(v.y) << 16);
      u32 hi = (u32)f2bf(v.z) | ((u32)f2bf(v.w) << 16);
      *(uint2*)(cnnb + (size_t)i * 4) = make_uint2(lo, hi);
    }
    return;
  }
  if (blk < 2688) {
    const int j = (blk - 2048) * 256 + tid;  // < 163840
    float4 v = ((const float4*)x)[j];
    const int bt = j >> 7, c = j & 127;
    const int b = bt / 20, t = bt - b * 20;
    u32 lo = (u32)f2bf(v.x) | ((u32)f2bf(v.y) << 16);
    u32 hi = (u32)f2bf(v.z) | ((u32)f2bf(v.w) << 16);
    *(uint2*)(xbT + ((size_t)t * NB + b) * 512 + c * 4) = make_uint2(lo, hi);
    return;
  }
  const int tb = blk - 2688;
  const float* src;
  u16* dst;
  int row_off, K, bx, by;
  if (tb < 1024) {
    int z = tb >> 8, r = tb & 255;
    bx = r & 15;
    by = r >> 4;
    src = z == 0 ? Wi : z == 1 ? Wf : z == 2 ? Wc : Wo;
    dst = wxt + (size_t)z * 512 * 512;
    row_off = 0;
    K = 512;
  } else if (tb < 2048) {
    int r = tb - 1024;
    bx = r & 63;
    by = r >> 6;
    src = Waf;
    dst = wbig;
    row_off = 0;
    K = 2048;
  } else if (tb < 6144) {
    int r = tb - 2048;
    int z = r >> 10, r2 = r & 1023;
    bx = r2 & 63;
    by = r2 >> 6;
    src = z == 0 ? Wi : z == 1 ? Wf : z == 2 ? Wc : Wo;
    dst = wbig + (size_t)512 * 2048 + (size_t)z * 512 * 2048;
    row_off = 1024;
    K = 2048;
  } else if (tb < 7168) {
    int r = tb - 6144;
    int z = r >> 8, r2 = r & 255;
    bx = r2 & 15;
    by = r2 >> 4;
    src = z == 0 ? Wi : z == 1 ? Wf : z == 2 ? Wc : Wo;
    dst = wcombT + (size_t)z * 512 * 512;
    row_off = 512;
    K = 512;
  } else {
    int r = tb - 7168;
    bx = r & 15;
    by = r >> 4;
    src = Wah;
    dst = wcombT + (size_t)2048 * 512;
    row_off = 0;
    K = 512;
  }
  const int k0 = bx * 32, n0 = by * 32;
  const int tx = tid & 31, ty = tid >> 5;  // 32 x 8
#pragma unroll
  for (int i = 0; i < 4; ++i)
    tile[ty + i * 8][tx] = src[(size_t)(row_off + k0 + ty + i * 8) * 512 + n0 + tx];
  __syncthreads();
#pragma unroll
  for (int i = 0; i < 4; ++i) {
    int n = n0 + ty + i * 8, k = k0 + tx;
    dst[(size_t)n * K + k] = f2bf(tile[tx][ty + i * 8]);
  }
}

// ===== gemm_all: heterogeneous. Blocks 0..489: 256^2 merged GEMM (R17 gemm256 body).
// ===== Blocks 490..649: xw 128^2 GEMM (512-thr variant), runs in gemm256's scheduling shadow.
#define STG(SS, CUR, K1)                                                                    \
  do {                                                                                      \
    _Pragma("unroll") for (int q_ = 0; q_ < 2; ++q_) {                                      \
      const u16* g_ = ((SS) < 2)                                                            \
                          ? (A + (size_t)(m0 + sR[SS][q_]) * K + (K1) + sC[SS][q_])         \
                          : (BT + (size_t)(n0 + sR[SS][q_]) * K + (K1) + sC[SS][q_]);       \
      gload_lds16(g_, lds + ((CUR) ^ 1) * 32768 + sL[SS][q_]);                              \
    }                                                                                       \
  } while (0)

#define PH(MF0, READB, CUR, DOSTAGE, SB, K1, WN)                                            \
  do {                                                                                      \
    const u16* pA_ = lds + (CUR) * 32768;                                                   \
    const u16* pB_ = pA_ + 16384;                                                           \
    bf16x8 af_[2][2];                                                                       \
    _Pragma("unroll") for (int kh_ = 0; kh_ < 2; ++kh_) {                                   \
      const int kc_ = kh_ * 4 + (lane >> 4);                                                \
      _Pragma("unroll") for (int ii_ = 0; ii_ < 2; ++ii_) {                                 \
        const int rA_ = wmH * 128 + ((MF0) + ii_) * 16 + l15;                               \
        af_[kh_][ii_] = *(const bf16x8*)(pA_ + rA_ * 64 + ((kc_ ^ (rA_ & 7)) * 8));         \
      }                                                                                     \
      if (READB) {                                                                          \
        _Pragma("unroll") for (int j_ = 0; j_ < 4; ++j_) {                                  \
          const int rB_ = wnq * 64 + j_ * 16 + l15;                                         \
          bg[kh_][j_] = *(const bf16x8*)(pB_ + rB_ * 64 + ((kc_ ^ (rB_ & 7)) * 8));         \
        }                                                                                   \
      }                                                                                     \
    }                                                                                       \
    if (DOSTAGE) {                                                                          \
      STG(SB, CUR, K1);                                                                     \
      STG((SB) + 1, CUR, K1);                                                               \
    }                                                                                       \
    vwait<WN>();                                                                            \
    __builtin_amdgcn_s_barrier();                                                           \
    __builtin_amdgcn_s_setprio(1);                                                          \
    _Pragma("unroll") for (int kh_ = 0; kh_ < 2; ++kh_)                                     \
      _Pragma("unroll") for (int ii_ = 0; ii_ < 2; ++ii_)                                   \
        _Pragma("unroll") for (int j_ = 0; j_ < 4; ++j_)                                    \
          acc[(MF0) + ii_][j_] = __builtin_amdgcn_mfma_f32_16x16x32_bf16(                   \
              af_[kh_][ii_], bg[kh_][j_], acc[(MF0) + ii_][j_], 0, 0, 0);                   \
    __builtin_amdgcn_s_setprio(0);                                                          \
    __builtin_amdgcn_s_barrier();                                                           \
  } while (0)

__global__ __launch_bounds__(512, 1) void gemm_all(
    const u16* __restrict__ A, const u16* __restrict__ BT, const float* __restrict__ bias,
    u16* __restrict__ fpb, u16* __restrict__ cnW, int K, int grid_n,
    const u16* __restrict__ xbT, const u16* __restrict__ wxt, float* __restrict__ xw) {
  __shared__ u16 lds[65536];  // big blocks: [buf][A|B] 128 KiB; xw blocks: first 32 KiB
  const int tid = threadIdx.x;
  const int lane = tid & 63;
  const int wid = tid >> 6;
  const int l15 = lane & 15;

  if (blockIdx.x >= 490) {
    // ---------- xw GEMM: [1280x512] @ [2048x512]^T -> f32 [1280][2048], 128^2 tile ----------
    const int bid2 = blockIdx.x - 490;
    const int mt2 = bid2 % 10, nt2 = bid2 / 10;
    const int m0 = mt2 * 128, n0 = nt2 * 128;
    const int wm = (wid >> 2) * 64, wn = (wid & 3) * 32;
    u16* lA = lds;
    u16* lB = lds + 8192;
    f32x4 acc2[4][2] = {};
    // staging: 1024 chunks of 16B per matrix, 2 per thread
    int r2[2], c2[2], lo2[2];
#pragma unroll
    for (int it = 0; it < 2; ++it) {
      int c = it * 512 + tid;
      r2[it] = c >> 3;
      c2[it] = ((c & 7) ^ ((c >> 3) & 7)) * 8;
      lo2[it] = (it * 512 + wid * 64) * 8;  // wave-uniform (+lane*16B by HW)
    }
    for (int k0 = 0; k0 < 512; k0 += 64) {
      __syncthreads();
#pragma unroll
      for (int it = 0; it < 2; ++it) {
        gload_lds16(xbT + (size_t)(m0 + r2[it]) * 512 + k0 + c2[it], lA + lo2[it]);
        gload_lds16(wxt + (size_t)(n0 + r2[it]) * 512 + k0 + c2[it], lB + lo2[it]);
      }
      vwait<0>();
      __syncthreads();
#pragma unroll
      for (int kk = 0; kk < 2; ++kk) {
        const int kchunk = kk * 4 + (lane >> 4);
        bf16x8 af[4], bg2[2];
#pragma unroll
        for (int i = 0; i < 4; ++i) {
          int row = wm + i * 16 + l15;
          af[i] = *(const bf16x8*)(lA + row * 64 + ((kchunk ^ (row & 7)) * 8));
        }
#pragma unroll
        for (int j = 0; j < 2; ++j) {
          int rowb = wn + j * 16 + l15;
          bg2[j] = *(const bf16x8*)(lB + rowb * 64 + ((kchunk ^ (rowb & 7)) * 8));
        }
#pragma unroll
        for (int i = 0; i < 4; ++i)
#pragma unroll
          for (int j = 0; j < 2; ++j)
            acc2[i][j] = __builtin_amdgcn_mfma_f32_16x16x32_bf16(af[i], bg2[j], acc2[i][j], 0,
                                                                 0, 0);
      }
    }
#pragma unroll
    for (int i = 0; i < 4; ++i) {
      int m = m0 + wm + i * 16 + ((lane >> 4) * 4);
#pragma unroll
      for (int j = 0; j < 2; ++j) {
        int n = n0 + wn + j * 16 + l15;
#pragma unroll
        for (int r = 0; r < 4; ++r) xw[(size_t)(m + r) * 2048 + n] = acc2[i][j][r];
      }
    }
    return;
  }

  // ---------- 256^2 merged GEMM (R17 body; swizzle over 490-block subspace) ----------
  const int nblk = 490;
  const int q = nblk >> 3, rr = nblk & 7;
  const int xcd = blockIdx.x & 7, jj = blockIdx.x >> 3;
  const int swz = (xcd < rr ? xcd * (q + 1) : rr * (q + 1) + (xcd - rr) * q) + jj;
  const int mt = swz / grid_n, nt = swz - mt * grid_n;
  const int m0 = mt * 256, n0 = nt * 256;
  const int wmH = wid >> 2;  // A-half (0/1): rows wmH*128..+128
  const int wnq = wid & 3;   // B quarter: cols wnq*64..+64
  f32x4 acc[8][4] = {};
  bf16x8 bg[2][4];  // B-frags read once per K-tile (ph0), carried through ph1-3

  int sR[4][2], sC[4][2], sL[4][2];
#pragma unroll
  for (int s = 0; s < 4; ++s)
#pragma unroll
    for (int qq = 0; qq < 2; ++qq) {
      int reg = (s < 2) ? s : s - 2;
      int ra = reg * 1024 + qq * 512 + wid * 64;  // wave-uniform chunk base in region
      int idx = ra + lane;
      sR[s][qq] = idx >> 3;
      sC[s][qq] = ((idx & 7) ^ ((idx >> 3) & 7)) * 8;
      sL[s][qq] = ((s < 2) ? 0 : 16384) + ra * 8;  // wave-uniform (+lane*16B by HW)
    }

  // prologue: stage k-tile 0 into buf0 (CUR=1 -> dest buf 0), drain, barrier
  STG(0, 1, 0);
  STG(1, 1, 0);
  STG(2, 1, 0);
  STG(3, 1, 0);
  vwait<0>();
  __builtin_amdgcn_s_barrier();

  const int KT = K >> 6;
  for (int kt = 0; kt < KT - 1; ++kt) {
    const int cur = kt & 1;
    const int k1 = (kt + 1) << 6;
    PH(0, 1, cur, 1, 0, k1, -1);  // B-frags + A0,1 ; stage A-slabs of kt+1
    PH(2, 0, cur, 1, 2, k1, -1);  // A2,3 ; stage B-slabs of kt+1
    PH(4, 0, cur, 0, 0, 0, -1);   // A4,5
    PH(6, 0, cur, 0, 0, 0, 0);    // A6,7 ; drain the 8 prefetch loads (~3 phases old)
  }
  {
    const int cur = (KT - 1) & 1;  // peeled last tile: no staging, nothing outstanding
    PH(0, 1, cur, 0, 0, 0, -1);
    PH(2, 0, cur, 0, 0, 0, -1);
    PH(4, 0, cur, 0, 0, 0, -1);
    PH(6, 0, cur, 0, 0, 0, -1);
  }

#pragma unroll
  for (int i = 0; i < 8; ++i) {
    int m = m0 + wmH * 128 + i * 16 + ((lane >> 4) * 4);
#pragma unroll
    for (int j = 0; j < 4; ++j) {
      int n = n0 + wnq * 64 + j * 16 + l15;
      float bv = (n < 512) ? bias[n] : 0.f;
#pragma unroll
      for (int r = 0; r < 4; ++r) {
        float val = acc[i][j][r] + bv;
        u32 me = (u32)(m + r);
        if (n < 512) {
          fpb[(size_t)me * 512 + n] = f2bf(val);
        } else {
          u32 bdx = me / 196u;
          u32 p = me - bdx * 196u;
          u32 g = (u32)(n - 512) >> 9;
          u32 n9 = (u32)(n - 512) & 511u;
          cnW[(((size_t)bdx * 4 + g) * 196 + p) * 512 + n9] = f2bf(val);
        }
      }
    }
  }
}

// ---------------- hproj: hp[64][2560] = h[64][512] @ wcT[2560][512]^T (f32 out) ----------------
__global__ __launch_bounds__(256) void hproj(const u16* __restrict__ hprev,
                                             const u16* __restrict__ wcT,
                                             float* __restrict__ hp) {
  const int ntile = blockIdx.x;
  const int tid = threadIdx.x, lane = tid & 63, kh = tid >> 6;
  const int l15 = lane & 15;
  const u16* Bp = wcT + (size_t)(ntile * 16 + l15) * 512 + kh * 128 + ((lane >> 4) * 8);
  const u16* Ap = hprev + (size_t)l15 * 512 + kh * 128 + ((lane >> 4) * 8);
  f32x4 acc[4] = {};
#pragma unroll
  for (int ks = 0; ks < 4; ++ks) {
    bf16x8 bb = *(const bf16x8*)(Bp + ks * 32);
#pragma unroll
    for (int mf = 0; mf < 4; ++mf) {
      bf16x8 a = *(const bf16x8*)(Ap + (size_t)mf * 16 * 512 + ks * 32);
      acc[mf] = __builtin_amdgcn_mfma_f32_16x16x32_bf16(a, bb, acc[mf], 0, 0, 0);
    }
  }
  __shared__ float pre[4][64][16];
  const int rrow = (lane >> 4) * 4;
#pragma unroll
  for (int mf = 0; mf < 4; ++mf)
#pragma unroll
    for (int r = 0; r < 4; ++r) pre[kh][mf * 16 + rrow + r][l15] = acc[mf][r];
  __syncthreads();
  const int m = tid >> 2, n = (tid & 3) * 4;
  float4 s;
  float* sp = (float*)&s;
#pragma unroll
  for (int j = 0; j < 4; ++j)
    sp[j] = pre[0][m][n + j] + pre[1][m][n + j] + pre[2][m][n + j] + pre[3][m][n + j];
  *(float4*)(hp + (size_t)m * 2560 + ntile * 16 + n) = s;
}

// ====== attn_gates: e + softmax + (alpha @ cnnW) + cell, one block per (b, n-quarter) ======
__global__ __launch_bounds__(1024) void attn_gates(
    const u16* __restrict__ fpb, const float* __restrict__ hp, const float* __restrict__ v,
    const u16* __restrict__ cw, const float* __restrict__ xw, const float* __restrict__ bi,
    const float* __restrict__ bfg, const float* __restrict__ bc, const float* __restrict__ bo,
    float* __restrict__ cbuf, float* __restrict__ out, u16* __restrict__ hnext, int t) {
  const int b = blockIdx.x & 63;
  const int quarter = blockIdx.x >> 6;  // 128 cols of [0,512)
  const int tid = threadIdx.x;
  const int lane = tid & 63, wid = tid >> 6;
  __shared__ float smem_a[1024];  // [0..511] hwa, [512..1023] vv; later pre4[4][128]
  __shared__ float sm[16];
  __shared__ float alp[200];
  __shared__ float red[8192];  // e[] in [0..255] first, then partials [4][16][16][8]

  float* hwa = smem_a;
  float* vv = smem_a + 512;
  if (tid < 512) {
    hwa[tid] = (t > 0) ? hp[(size_t)b * 2560 + 2048 + tid] : 0.f;
    vv[tid] = v[tid];
  }
  if (tid >= 196 && tid < 256) red[tid] = -3e38f;
  __syncthreads();

  // ---- e[p] = sum_a tanh(fp + hwa) * v ----
  float hw[8], vr[8];
#pragma unroll
  for (int j = 0; j < 8; ++j) {
    hw[j] = hwa[lane * 8 + j];
    vr[j] = vv[lane * 8 + j];
  }
  for (int p = wid; p < NP; p += 16) {
    const u16* fp = fpb + ((size_t)b * NP + p) * 512 + lane * 8;
    uint4 raw = *(const uint4*)fp;
    u32 w[4] = {raw.x, raw.y, raw.z, raw.w};
    float part = 0.f;
#pragma unroll
    for (int j = 0; j < 8; ++j) {
      u16 u = (u16)(w[j >> 1] >> ((j & 1) * 16));
      part += tanh_fast(bf2f(u) + hw[j]) * vr[j];
    }
#pragma unroll
    for (int off = 32; off > 0; off >>= 1) part += __shfl_xor(part, off);
    if (lane == 0) red[p] = part;
  }
  __syncthreads();

  // ---- softmax over 196: wave-level reduce (4 waves hold the 256 padded e-values) ----
  float ev = 0.f, w = 0.f;
  if (tid < 256) {
    ev = red[tid];
    float m_ = ev;
#pragma unroll
    for (int off = 32; off > 0; off >>= 1) m_ = fmaxf(m_, __shfl_xor(m_, off));
    if (lane == 0) sm[wid] = m_;
  }
  __syncthreads();
  if (tid < 256) {
    float mx = fmaxf(fmaxf(sm[0], sm[1]), fmaxf(sm[2], sm[3]));
    w = (tid < NP) ? __builtin_amdgcn_exp2f((ev - mx) * 1.44269504f) : 0.f;
    float s_ = w;
#pragma unroll
    for (int off = 32; off > 0; off >>= 1) s_ += __shfl_xor(s_, off);
    if (lane == 0) sm[8 + wid] = s_;
  }
  __syncthreads();
  if (tid < NP) {
    float tot = (sm[8] + sm[9]) + (sm[10] + sm[11]);
    alp[tid] = w * __builtin_amdgcn_rcpf(tot);
  }
  __syncthreads();

  // ---- gate pre-activation: pre[g][n'] = sum_p alpha[p]*cnnW[b][g][p][quarter*128+n'] ----
  {
    const int g = tid >> 8, pg = (tid >> 4) & 15, colc = tid & 15;
    const u16* base = cw + ((size_t)(b * 4 + g) * 196) * 512 + quarter * 128 + colc * 8;
    float acc[8] = {};
    for (int i = 0; i < 13; ++i) {
      int p = pg + i * 16;
      if (p < NP) {
        float al = alp[p];
        uint4 raw = *(const uint4*)(base + (size_t)p * 512);
        u32 wds[4] = {raw.x, raw.y, raw.z, raw.w};
#pragma unroll
        for (int j = 0; j < 8; ++j) acc[j] += al * bf2f((u16)(wds[j >> 1] >> ((j & 1) * 16)));
      }
    }
#pragma unroll
    for (int j = 0; j < 8; ++j) red[((g * 16 + pg) * 16 + colc) * 8 + j] = acc[j];
  }
  __syncthreads();

  // reduce over pg into pre4 (aliases smem_a)
  float* pre4 = smem_a;
  if (tid < 512) {
    const int gg = tid >> 7, nn = tid & 127;
    float s = 0.f;
#pragma unroll
    for (int pg2 = 0; pg2 < 16; ++pg2)
      s += red[((gg * 16 + pg2) * 16 + (nn >> 3)) * 8 + (nn & 7)];
    pre4[gg * 128 + nn] = s;
  }
  __syncthreads();

  // ---- LSTM cell for this quarter's 128 columns ----
  if (tid < 128) {
    const int ng = quarter * 128 + tid;
    const size_t xwo = ((size_t)t * NB + b) * 2048;
    const size_t hpb = (size_t)b * 2560;
    float hwh0 = 0.f, hwh1 = 0.f, hwh2 = 0.f, hwh3 = 0.f;
    if (t > 0) {
      hwh0 = hp[hpb + ng];
      hwh1 = hp[hpb + 512 + ng];
      hwh2 = hp[hpb + 1024 + ng];
      hwh3 = hp[hpb + 1536 + ng];
    }
    float ip = pre4[0 * 128 + tid] + xw[xwo + ng] + hwh0 + bi[ng];
    float fp = pre4[1 * 128 + tid] + xw[xwo + 512 + ng] + hwh1 + bfg[ng];
    float cp = pre4[2 * 128 + tid] + xw[xwo + 1024 + ng] + hwh2 + bc[ng];
    float op = pre4[3 * 128 + tid] + xw[xwo + 1536 + ng] + hwh3 + bo[ng];
    float it = sigmoid_fast(ip), ft = sigmoid_fast(fp), ot = sigmoid_fast(op);
    float ctl = tanh_fast(cp);
    float cold = (t > 0) ? cbuf[(size_t)b * 512 + ng] : 0.f;
    float cn = ft * cold + it * ctl;
    float hn = ot * tanh_fast(cn);
    cbuf[(size_t)b * 512 + ng] = cn;
    hnext[(size_t)b * 512 + ng] = f2bf(hn);
    out[((size_t)b * NT + t) * 512 + ng] = hn;
    if (t == NT - 1) {
      out[(size_t)NB * NT * 512 + (size_t)b * 512 + ng] = hn;
      out[(size_t)NB * NT * 512 + (size_t)NB * 512 + (size_t)b * 512 + ng] = cn;
    }
  }
}

// ======================= host launcher =======================
extern "C" void kernel_launch(void* const* d_in, const int* in_sizes, int n_in, void* d_out,
                              int out_size, void* d_ws, size_t ws_size, hipStream_t stream) {
  const float* x = (const float*)d_in[0];
  const float* cnn = (const float*)d_in[1];
  const float* Wi = (const float*)d_in[2];
  const float* bi = (const float*)d_in[3];
  const float* Wf = (const float*)d_in[4];
  const float* bfv = (const float*)d_in[5];
  const float* Wc = (const float*)d_in[6];
  const float* bc = (const float*)d_in[7];
  const float* Wo = (const float*)d_in[8];
  const float* bo = (const float*)d_in[9];
  const float* Waf = (const float*)d_in[10];
  const float* Wah = (const float*)d_in[11];
  const float* ba = (const float*)d_in[12];
  const float* v = (const float*)d_in[13];
  float* out = (float*)d_out;

  char* base = (char*)d_ws;
  size_t off = 0;
  auto alloc = [&](size_t bytes) {
    char* r = base + off;
    off += (bytes + 255) & ~(size_t)255;
    return r;
  };
  u16* cnnb = (u16*)alloc((size_t)NB * NP * NE * 2);      // 51.4 MB
  u16* fpb = (u16*)alloc((size_t)NB * NP * NA * 2);       // 12.8 MB
  u16* cnW = (u16*)alloc((size_t)NB * 4 * NP * 512 * 2);  // 51.4 MB [b][g][p][n']
  u16* wbig = (u16*)alloc((size_t)2560 * 2048 * 2);       // 10.5 MB [512 Wa_feat^T | 2048 Wctx^T]
  u16* wcombT = (u16*)alloc((size_t)2560 * 512 * 2);      // 2.6 MB  [2048 hWh | 512 hWa][512]
  u16* wxt = (u16*)alloc((size_t)4 * 512 * 512 * 2);      // 2 MB
  u16* xbT = (u16*)alloc((size_t)NT * NB * 512 * 2);      // 1.3 MB  [t][b][512]
  float* xw = (float*)alloc((size_t)NT * NB * 2048 * 4);  // 10.5 MB [t][b][2048]
  u16* hbuf = (u16*)alloc((size_t)2 * NB * 512 * 2);      // 128 KB (double buffer)
  float* cbuf = (float*)alloc((size_t)NB * 512 * 4);      // 128 KB
  float* hp = (float*)alloc((size_t)NB * 2560 * 4);       // 656 KB [b][hWh 2048 | hWa 512]

  (void)ws_size;
  (void)in_sizes;
  (void)n_in;
  (void)out_size;

  // all preprocessing in one launch
  prep_all<<<10112, 256, 0, stream>>>((const float4*)cnn, x, Wi, Wf, Wc, Wo, Waf, Wah, cnnb, xbT,
                                      wxt, wbig, wcombT);

  // merged GEMMs: blocks 0..489 = [fpb|cnW] (M=12544,N=2560,K=2048); 490..649 = xw GEMM
  gemm_all<<<650, 512, 0, stream>>>(cnnb, wbig, ba, fpb, cnW, 2048, 10, xbT, wxt, xw);

  // 20-step recurrence: hproj (t>0) + fused attn/gates
  for (int t = 0; t < NT; ++t) {
    const u16* hprev = hbuf + (size_t)(t & 1) * NB * 512;
    u16* hnext = hbuf + (size_t)((t + 1) & 1) * NB * 512;
    if (t > 0) hproj<<<160, 256, 0, stream>>>(hprev, wcombT, hp);
    attn_gates<<<256, 1024, 0, stream>>>(fpb, hp, v, cnW, xw, bi, bfv, bc, bo, cbuf, out, hnext,
                                         t);
  }
}